// Round 2
// baseline (7914.411 us; speedup 1.0000x reference)
//
#include <hip/hip_runtime.h>

#define B 32
#define S 2048
#define I 256
#define H 256

typedef _Float16 h2 __attribute__((ext_vector_type(2)));

__device__ __forceinline__ float fdot2(h2 a, h2 b, float c) {
#if __has_builtin(__builtin_amdgcn_fdot2)
    return __builtin_amdgcn_fdot2(a, b, c, false);
#else
    return fmaf((float)a[1], (float)b[1], fmaf((float)a[0], (float)b[0], c));
#endif
}

// Workgroup barrier that only waits on LDS (lgkmcnt(0)), NOT vmcnt.
// __syncthreads() emits s_waitcnt vmcnt(0) before s_barrier, which drains the
// per-step output store + xw prefetch load (~500 cyc/step). Our global ops are
// thread-private (each thread owns its own output column), so only LDS needs
// cross-wave visibility. imm 0xC07F = vmcnt(63) expcnt(7) lgkmcnt(0).
__device__ __forceinline__ void lds_barrier() {
    __asm__ __volatile__("" ::: "memory");
    __builtin_amdgcn_s_waitcnt(0xC07F);
    __builtin_amdgcn_s_barrier();
    __asm__ __volatile__("" ::: "memory");
}

__device__ __forceinline__ float fast_tanh(float x) {
    // tanh(x) = 1 - 2/(exp(2x)+1); v_exp_f32-based, ~1e-6 abs err
    float e = __expf(2.0f * x);
    return 1.0f - __fdividef(2.0f, e + 1.0f);
}

// ---------------------------------------------------------------------------
// Phase 1: xw[m][n] = sum_k x[m][k] * Wxw[n][k] + Wxb[n]   (unchanged from R1)
// ---------------------------------------------------------------------------
#define TM 64
#define TN 64
#define TK 32

__global__ __launch_bounds__(256) void phase1_gemm(
    const float* __restrict__ x, const float* __restrict__ Wxw,
    const float* __restrict__ Wxb, float* __restrict__ out)
{
    __shared__ __align__(16) float As[TK][TM + 4];
    __shared__ __align__(16) float Bs[TK][TN + 4];

    const int t  = threadIdx.x;
    const int tn = t & 15, tm = t >> 4;
    const int m0 = blockIdx.x * TM;
    const int n0 = blockIdx.y * TN;

    float acc[4][4] = {};
    float bias[4];
#pragma unroll
    for (int j = 0; j < 4; ++j) bias[j] = Wxb[n0 + 4 * tn + j];

    const int lr = t >> 3;
    const int lc = t & 7;

    for (int kt = 0; kt < I; kt += TK) {
#pragma unroll
        for (int hh = 0; hh < 2; ++hh) {
            const int m = lr + 32 * hh;
            float4 v = *(const float4*)(x   + (size_t)(m0 + m) * I + kt + 4 * lc);
            As[4 * lc + 0][m] = v.x; As[4 * lc + 1][m] = v.y;
            As[4 * lc + 2][m] = v.z; As[4 * lc + 3][m] = v.w;
            float4 w = *(const float4*)(Wxw + (size_t)(n0 + m) * I + kt + 4 * lc);
            Bs[4 * lc + 0][m] = w.x; Bs[4 * lc + 1][m] = w.y;
            Bs[4 * lc + 2][m] = w.z; Bs[4 * lc + 3][m] = w.w;
        }
        __syncthreads();
#pragma unroll
        for (int k = 0; k < TK; ++k) {
            float4 a = *(const float4*)&As[k][4 * tm];
            float4 b = *(const float4*)&Bs[k][4 * tn];
            float av[4] = {a.x, a.y, a.z, a.w};
            float bv[4] = {b.x, b.y, b.z, b.w};
#pragma unroll
            for (int i2 = 0; i2 < 4; ++i2)
#pragma unroll
                for (int j = 0; j < 4; ++j)
                    acc[i2][j] = fmaf(av[i2], bv[j], acc[i2][j]);
        }
        __syncthreads();
    }
#pragma unroll
    for (int i2 = 0; i2 < 4; ++i2) {
        float4 v = { acc[i2][0] + bias[0], acc[i2][1] + bias[1],
                     acc[i2][2] + bias[2], acc[i2][3] + bias[3] };
        *(float4*)(out + (size_t)(m0 + 4 * tm + i2) * H + n0 + 4 * tn) = v;
    }
}

// ---------------------------------------------------------------------------
// Phase 2: per-batch recurrence h = tanh(xw_s + h @ Whw^T), 2048 steps.
// 32 blocks x 256 threads; thread k owns output k, W row k in 128 h2 VGPRs.
// Raw lgkm-only barrier (no vmcnt drain), 2-deep xw prefetch, unroll capped
// at 8 so the allocator keeps wreg in ArchVGPRs (no AGPR round-trips).
// ---------------------------------------------------------------------------
__device__ __forceinline__ float rnn_step(const h2* wreg, const _Float16* hsrc,
                                          float xw) {
    const uint4* hp = (const uint4*)hsrc;
    float a0 = 0.f, a1 = 0.f, a2 = 0.f, a3 = 0.f;
#pragma unroll 8
    for (int u = 0; u < H / 8; ++u) {   // 32 iters, one uint4 (8 halves) each
        uint4 v = hp[u];
        h2 p0 = __builtin_bit_cast(h2, v.x);
        h2 p1 = __builtin_bit_cast(h2, v.y);
        h2 p2 = __builtin_bit_cast(h2, v.z);
        h2 p3 = __builtin_bit_cast(h2, v.w);
        a0 = fdot2(wreg[4 * u + 0], p0, a0);
        a1 = fdot2(wreg[4 * u + 1], p1, a1);
        a2 = fdot2(wreg[4 * u + 2], p2, a2);
        a3 = fdot2(wreg[4 * u + 3], p3, a3);
    }
    return fast_tanh(xw + (a0 + a1) + (a2 + a3));
}

__global__ __launch_bounds__(256, 1) void phase2_rnn(
    const float* __restrict__ Whw, float* __restrict__ out)
{
    __shared__ __align__(16) _Float16 hbuf[2][H];

    const int b = blockIdx.x;
    const int k = threadIdx.x;

    // W row k -> 128 h2 registers (one-time; unroll capped to limit pressure)
    h2 wreg[H / 2];
    const float4* wp = (const float4*)(Whw + (size_t)k * H);
#pragma unroll 8
    for (int i = 0; i < H / 4; ++i) {
        float4 f = wp[i];
        wreg[2 * i]     = h2{(_Float16)f.x, (_Float16)f.y};
        wreg[2 * i + 1] = h2{(_Float16)f.z, (_Float16)f.w};
    }

    hbuf[0][k] = (_Float16)0.0f;
    lds_barrier();

    float* outb = out + (size_t)b * S * H + k;
    float*       op = outb;              // per-step store cursor
    const float* lp = outb + 2 * (size_t)H;  // prefetch cursor (step s+2)

    // 2-deep prefetch pipeline. Reads up to 2 steps past the end land in the
    // h_last region of d_out (valid memory); values are never used.
    float xw0 = outb[0];
    float xw1 = outb[(size_t)H];

    float hv = 0.f;
    for (int s = 0; s < S; s += 2) {
        float xwl0 = lp[0];               // for step s+2
        hv = rnn_step(wreg, hbuf[0], xw0);    // even step: reads hbuf[0]
        hbuf[1][k] = (_Float16)hv;
        op[0] = hv; op += H;
        lds_barrier();

        float xwl1 = lp[(size_t)H];       // for step s+3
        lp += 2 * (size_t)H;
        hv = rnn_step(wreg, hbuf[1], xw1);    // odd step: reads hbuf[1]
        hbuf[0][k] = (_Float16)hv;
        op[0] = hv; op += H;
        lds_barrier();

        xw0 = xwl0; xw1 = xwl1;
    }
    // h_last = h at s = S-1
    out[(size_t)B * S * H + (size_t)b * H + k] = hv;
}

// ---------------------------------------------------------------------------
extern "C" void kernel_launch(void* const* d_in, const int* in_sizes, int n_in,
                              void* d_out, int out_size, void* d_ws, size_t ws_size,
                              hipStream_t stream) {
    const float* x   = (const float*)d_in[0];
    const float* Wxw = (const float*)d_in[1];
    const float* Wxb = (const float*)d_in[2];
    const float* Whw = (const float*)d_in[3];
    float* out = (float*)d_out;

    dim3 g1(B * S / TM, H / TN);   // 1024 x 4
    phase1_gemm<<<g1, 256, 0, stream>>>(x, Wxw, Wxb, out);
    phase2_rnn<<<B, 256, 0, stream>>>(Whw, out);
}

// Round 3
// 1394.520 us; speedup vs baseline: 5.6754x; 5.6754x over previous
//
#include <hip/hip_runtime.h>

#define B 32
#define S 2048
#define I 256
#define H 256

typedef _Float16 h2 __attribute__((ext_vector_type(2)));

__device__ __forceinline__ float fdot2(h2 a, h2 b, float c) {
#if __has_builtin(__builtin_amdgcn_fdot2)
    return __builtin_amdgcn_fdot2(a, b, c, false);
#else
    return fmaf((float)a[1], (float)b[1], fmaf((float)a[0], (float)b[0], c));
#endif
}

// Workgroup barrier that only waits on LDS (lgkmcnt(0)), NOT vmcnt.
// __syncthreads() drains vmcnt(0) before s_barrier, eating a store-ack round
// trip every step. Our global loads/stores are thread-private columns, so only
// LDS needs cross-wave visibility. imm 0xC07F = vmcnt(63) expcnt(7) lgkmcnt(0).
__device__ __forceinline__ void lds_barrier() {
    __asm__ __volatile__("" ::: "memory");
    __builtin_amdgcn_s_waitcnt(0xC07F);
    __builtin_amdgcn_s_barrier();
    __asm__ __volatile__("" ::: "memory");
}

__device__ __forceinline__ float fast_tanh(float x) {
    // tanh(x) = 1 - 2/(exp(2x)+1); v_exp_f32-based, ~1e-6 abs err
    float e = __expf(2.0f * x);
    return 1.0f - __fdividef(2.0f, e + 1.0f);
}

// ---------------------------------------------------------------------------
// Phase 1: xw[m][n] = sum_k x[m][k] * Wxw[n][k] + Wxb[n]   (unchanged)
// ---------------------------------------------------------------------------
#define TM 64
#define TN 64
#define TK 32

__global__ __launch_bounds__(256) void phase1_gemm(
    const float* __restrict__ x, const float* __restrict__ Wxw,
    const float* __restrict__ Wxb, float* __restrict__ out)
{
    __shared__ __align__(16) float As[TK][TM + 4];
    __shared__ __align__(16) float Bs[TK][TN + 4];

    const int t  = threadIdx.x;
    const int tn = t & 15, tm = t >> 4;
    const int m0 = blockIdx.x * TM;
    const int n0 = blockIdx.y * TN;

    float acc[4][4] = {};
    float bias[4];
#pragma unroll
    for (int j = 0; j < 4; ++j) bias[j] = Wxb[n0 + 4 * tn + j];

    const int lr = t >> 3;
    const int lc = t & 7;

    for (int kt = 0; kt < I; kt += TK) {
#pragma unroll
        for (int hh = 0; hh < 2; ++hh) {
            const int m = lr + 32 * hh;
            float4 v = *(const float4*)(x   + (size_t)(m0 + m) * I + kt + 4 * lc);
            As[4 * lc + 0][m] = v.x; As[4 * lc + 1][m] = v.y;
            As[4 * lc + 2][m] = v.z; As[4 * lc + 3][m] = v.w;
            float4 w = *(const float4*)(Wxw + (size_t)(n0 + m) * I + kt + 4 * lc);
            Bs[4 * lc + 0][m] = w.x; Bs[4 * lc + 1][m] = w.y;
            Bs[4 * lc + 2][m] = w.z; Bs[4 * lc + 3][m] = w.w;
        }
        __syncthreads();
#pragma unroll
        for (int k = 0; k < TK; ++k) {
            float4 a = *(const float4*)&As[k][4 * tm];
            float4 b = *(const float4*)&Bs[k][4 * tn];
            float av[4] = {a.x, a.y, a.z, a.w};
            float bv[4] = {b.x, b.y, b.z, b.w};
#pragma unroll
            for (int i2 = 0; i2 < 4; ++i2)
#pragma unroll
                for (int j = 0; j < 4; ++j)
                    acc[i2][j] = fmaf(av[i2], bv[j], acc[i2][j]);
        }
        __syncthreads();
    }
#pragma unroll
    for (int i2 = 0; i2 < 4; ++i2) {
        float4 v = { acc[i2][0] + bias[0], acc[i2][1] + bias[1],
                     acc[i2][2] + bias[2], acc[i2][3] + bias[3] };
        *(float4*)(out + (size_t)(m0 + 4 * tm + i2) * H + n0 + 4 * tn) = v;
    }
}

// ---------------------------------------------------------------------------
// Phase 2: per-batch recurrence h = tanh(xw_s + h @ Whw^T), 2048 steps.
// 32 blocks x 512 threads (8 waves). K split across two 256-thread halves:
//   thread t: row r = t&255, half = t>>8, holds Whw[r][128*half .. +128) in
//   64 h2 VGPRs (FULL unroll -> constant indices -> SROA keeps it in regs;
//   the R2 "#pragma unroll 8" demoted the array to scratch: VGPR=40, 4.8x
//   regression).
// Per step: 64 fdot2 -> fp32 partial -> LDS -> low half combines, tanh,
// writes h (fp16, double-buffered) + output column. Two lgkm-only barriers.
// ---------------------------------------------------------------------------
#define NT 512

__global__ __launch_bounds__(NT, 2) void phase2_rnn(
    const float* __restrict__ Whw, float* __restrict__ out)
{
    __shared__ __align__(16) _Float16 hbuf[2][H];
    __shared__ __align__(16) float    pbuf[NT];

    const int b    = blockIdx.x;
    const int t    = threadIdx.x;
    const int r    = t & (H - 1);
    const int half = t >> 8;          // 0: k in [0,128), 1: k in [128,256)

    // 64 h2 weight registers (half a row), one-time load. Full unroll.
    h2 wreg[64];
    const float4* wp = (const float4*)(Whw + (size_t)r * H + 128 * half);
#pragma unroll
    for (int i = 0; i < 32; ++i) {
        float4 f = wp[i];
        wreg[2 * i]     = h2{(_Float16)f.x, (_Float16)f.y};
        wreg[2 * i + 1] = h2{(_Float16)f.z, (_Float16)f.w};
    }

    if (half == 0) hbuf[0][r] = (_Float16)0.0f;
    lds_barrier();

    // xw column pointers (low half only). 2-deep prefetch: reads up to 2 steps
    // past the end land in the h_last region / next batch's xw (valid memory,
    // values never used).
    float* outb = out + (size_t)b * S * H + r;
    float*       op = outb;
    const float* lp = outb + 2 * (size_t)H;
    float xw0 = 0.f, xw1 = 0.f;
    if (half == 0) { xw0 = outb[0]; xw1 = outb[(size_t)H]; }

    float hv = 0.f;
    for (int s = 0; s < S; ++s) {
        float xwn = 0.f;
        if (half == 0) { xwn = lp[0]; lp += H; }   // prefetch step s+2

        const uint4* hp = (const uint4*)(&hbuf[s & 1][0] + 128 * half);
        float a0 = 0.f, a1 = 0.f, a2 = 0.f, a3 = 0.f;
#pragma unroll
        for (int u = 0; u < 16; ++u) {      // 16 x (1 uint4 = 8 halves)
            uint4 v = hp[u];
            a0 = fdot2(wreg[4 * u + 0], __builtin_bit_cast(h2, v.x), a0);
            a1 = fdot2(wreg[4 * u + 1], __builtin_bit_cast(h2, v.y), a1);
            a2 = fdot2(wreg[4 * u + 2], __builtin_bit_cast(h2, v.z), a2);
            a3 = fdot2(wreg[4 * u + 3], __builtin_bit_cast(h2, v.w), a3);
        }
        pbuf[t] = (a0 + a1) + (a2 + a3);
        lds_barrier();

        if (half == 0) {
            float sum = pbuf[r] + pbuf[r + H];
            hv = fast_tanh(xw0 + sum);
            op[0] = hv; op += H;             // outputs[b,s,r]
            hbuf[(s & 1) ^ 1][r] = (_Float16)hv;
        }
        lds_barrier();

        xw0 = xw1; xw1 = xwn;
    }
    if (half == 0)
        out[(size_t)B * S * H + (size_t)b * H + r] = hv;   // h_last
}

// ---------------------------------------------------------------------------
extern "C" void kernel_launch(void* const* d_in, const int* in_sizes, int n_in,
                              void* d_out, int out_size, void* d_ws, size_t ws_size,
                              hipStream_t stream) {
    const float* x   = (const float*)d_in[0];
    const float* Wxw = (const float*)d_in[1];
    const float* Wxb = (const float*)d_in[2];
    const float* Whw = (const float*)d_in[3];
    float* out = (float*)d_out;

    dim3 g1(B * S / TM, H / TN);   // 1024 x 4
    phase1_gemm<<<g1, 256, 0, stream>>>(x, Wxw, Wxb, out);
    phase2_rnn<<<B, NT, 0, stream>>>(Whw, out);
}

// Round 4
// 1198.070 us; speedup vs baseline: 6.6060x; 1.1640x over previous
//
#include <hip/hip_runtime.h>

#define B 32
#define S 2048
#define I 256
#define H 256

typedef _Float16 h2 __attribute__((ext_vector_type(2)));

__device__ __forceinline__ float fdot2(h2 a, h2 b, float c) {
#if __has_builtin(__builtin_amdgcn_fdot2)
    return __builtin_amdgcn_fdot2(a, b, c, false);
#else
    return fmaf((float)a[1], (float)b[1], fmaf((float)a[0], (float)b[0], c));
#endif
}

// lgkm-only workgroup barrier: __syncthreads() drains vmcnt(0) before
// s_barrier; our per-step global ops are thread-private columns so only LDS
// needs cross-wave visibility. imm 0xC07F = vmcnt(63) expcnt(7) lgkmcnt(0).
__device__ __forceinline__ void lds_barrier() {
    __asm__ __volatile__("" ::: "memory");
    __builtin_amdgcn_s_waitcnt(0xC07F);
    __builtin_amdgcn_s_barrier();
    __asm__ __volatile__("" ::: "memory");
}

__device__ __forceinline__ float fast_tanh(float x) {
    float e = __expf(2.0f * x);
    return 1.0f - __fdividef(2.0f, e + 1.0f);
}

// ---------------------------------------------------------------------------
// Phase 1: xw[m][n] = sum_k x[m][k]*Wxw[n][k] + Wxb[n]   (unchanged)
// ---------------------------------------------------------------------------
#define TM 64
#define TN 64
#define TK 32

__global__ __launch_bounds__(256) void phase1_gemm(
    const float* __restrict__ x, const float* __restrict__ Wxw,
    const float* __restrict__ Wxb, float* __restrict__ out)
{
    __shared__ __align__(16) float As[TK][TM + 4];
    __shared__ __align__(16) float Bs[TK][TN + 4];

    const int t  = threadIdx.x;
    const int tn = t & 15, tm = t >> 4;
    const int m0 = blockIdx.x * TM;
    const int n0 = blockIdx.y * TN;

    float acc[4][4] = {};
    float bias[4];
#pragma unroll
    for (int j = 0; j < 4; ++j) bias[j] = Wxb[n0 + 4 * tn + j];

    const int lr = t >> 3;
    const int lc = t & 7;

    for (int kt = 0; kt < I; kt += TK) {
#pragma unroll
        for (int hh = 0; hh < 2; ++hh) {
            const int m = lr + 32 * hh;
            float4 v = *(const float4*)(x   + (size_t)(m0 + m) * I + kt + 4 * lc);
            As[4 * lc + 0][m] = v.x; As[4 * lc + 1][m] = v.y;
            As[4 * lc + 2][m] = v.z; As[4 * lc + 3][m] = v.w;
            float4 w = *(const float4*)(Wxw + (size_t)(n0 + m) * I + kt + 4 * lc);
            Bs[4 * lc + 0][m] = w.x; Bs[4 * lc + 1][m] = w.y;
            Bs[4 * lc + 2][m] = w.z; Bs[4 * lc + 3][m] = w.w;
        }
        __syncthreads();
#pragma unroll
        for (int k = 0; k < TK; ++k) {
            float4 a = *(const float4*)&As[k][4 * tm];
            float4 b = *(const float4*)&Bs[k][4 * tn];
            float av[4] = {a.x, a.y, a.z, a.w};
            float bv[4] = {b.x, b.y, b.z, b.w};
#pragma unroll
            for (int i2 = 0; i2 < 4; ++i2)
#pragma unroll
                for (int j = 0; j < 4; ++j)
                    acc[i2][j] = fmaf(av[i2], bv[j], acc[i2][j]);
        }
        __syncthreads();
    }
#pragma unroll
    for (int i2 = 0; i2 < 4; ++i2) {
        float4 v = { acc[i2][0] + bias[0], acc[i2][1] + bias[1],
                     acc[i2][2] + bias[2], acc[i2][3] + bias[3] };
        *(float4*)(out + (size_t)(m0 + 4 * tm + i2) * H + n0 + 4 * tn) = v;
    }
}

// ---------------------------------------------------------------------------
// Phase 2: h = tanh(xw_s + h @ Whw^T), 2048 steps. 32 blocks x 256 threads.
//
// R3 was LDS-broadcast-bound: 128 ds_read_b128/step/CU (~11 cyc each) = 1414
// cyc/step. Fix: 4 rows/thread amortizes the h broadcast 4x (32 instrs/step).
//   wave w owns k-segment [64w, 64w+64)
//   thread (w, g=lane) computes partials for rows 4g..4g+3 over its k-seg
//     -> W[4g..4g+3][64w..64w+64) lives in 128 h2 VGPRs (full unroll!)
//   partial write: ONE conflict-free ds_write float4 (rows 4g..4g+3 contig)
//   ONE lgkm-only barrier, then thread t reduces row t (4 reads, stride-1,
//   conflict-free), tanh, writes h[t].
// No second barrier: wave w consumes h[64w..64w+64) next step, which is
// written by wave w's own lanes -> wave-local lgkm ordering suffices.
// pbuf double-buffered so next step's partial writes can't race readers.
// ---------------------------------------------------------------------------
__global__ __launch_bounds__(256, 1) void phase2_rnn(
    const float* __restrict__ Whw, float* __restrict__ out)
{
    __shared__ __align__(16) _Float16 hsh[H];          // single-buffered h
    __shared__ __align__(16) float    pbuf[2][4][H];   // K-partials, dbuf

    const int b = blockIdx.x;
    const int t = threadIdx.x;
    const int w = t >> 6;   // wave id = K-segment
    const int g = t & 63;   // lane -> rows 4g..4g+3

    // wreg[i][j] = W[4g+i][64w + 2j .. 2j+1] as h2. Constant indices only.
    h2 wreg[4][32];
#pragma unroll
    for (int i = 0; i < 4; ++i) {
        const float4* wp = (const float4*)(Whw + (size_t)(4 * g + i) * H + 64 * w);
#pragma unroll
        for (int q = 0; q < 16; ++q) {
            float4 f = wp[q];
            wreg[i][2 * q]     = h2{(_Float16)f.x, (_Float16)f.y};
            wreg[i][2 * q + 1] = h2{(_Float16)f.z, (_Float16)f.w};
        }
    }

    hsh[t] = (_Float16)0.0f;
    lds_barrier();

    // xw column t of batch b, read/written in place in d_out. 2-deep prefetch;
    // reads up to 2 steps past the end land in the h_last region (in bounds,
    // values unused).
    float* outb = out + (size_t)b * S * H + t;
    float*       op = outb;
    const float* lp = outb + 2 * (size_t)H;
    float xw0 = outb[0], xw1 = outb[(size_t)H];

    float hv = 0.f;
    for (int s = 0; s < S; ++s) {
        const int p = s & 1;
        float xwn = lp[0]; lp += H;          // prefetch xw for step s+2

        // MAC: 4 rows x 64 k (own k-segment), h via wave-broadcast b128 reads
        const uint4* hp = (const uint4*)(hsh + 64 * w);
        float acc0 = 0.f, acc1 = 0.f, acc2 = 0.f, acc3 = 0.f;
#pragma unroll
        for (int u = 0; u < 8; ++u) {        // uint4 u covers k = 8u..8u+7
            uint4 v = hp[u];
            h2 q0 = __builtin_bit_cast(h2, v.x);
            h2 q1 = __builtin_bit_cast(h2, v.y);
            h2 q2 = __builtin_bit_cast(h2, v.z);
            h2 q3 = __builtin_bit_cast(h2, v.w);
            acc0 = fdot2(wreg[0][4 * u + 0], q0, acc0);
            acc0 = fdot2(wreg[0][4 * u + 1], q1, acc0);
            acc0 = fdot2(wreg[0][4 * u + 2], q2, acc0);
            acc0 = fdot2(wreg[0][4 * u + 3], q3, acc0);
            acc1 = fdot2(wreg[1][4 * u + 0], q0, acc1);
            acc1 = fdot2(wreg[1][4 * u + 1], q1, acc1);
            acc1 = fdot2(wreg[1][4 * u + 2], q2, acc1);
            acc1 = fdot2(wreg[1][4 * u + 3], q3, acc1);
            acc2 = fdot2(wreg[2][4 * u + 0], q0, acc2);
            acc2 = fdot2(wreg[2][4 * u + 1], q1, acc2);
            acc2 = fdot2(wreg[2][4 * u + 2], q2, acc2);
            acc2 = fdot2(wreg[2][4 * u + 3], q3, acc2);
            acc3 = fdot2(wreg[3][4 * u + 0], q0, acc3);
            acc3 = fdot2(wreg[3][4 * u + 1], q1, acc3);
            acc3 = fdot2(wreg[3][4 * u + 2], q2, acc3);
            acc3 = fdot2(wreg[3][4 * u + 3], q3, acc3);
        }
        // partials for rows 4g..4g+3: one float4, conflict-free
        float4 part = {acc0, acc1, acc2, acc3};
        *(float4*)&pbuf[p][w][4 * g] = part;

        lds_barrier();

        // thread t reduces row t (stride-1 reads, conflict-free)
        float sum = (pbuf[p][0][t] + pbuf[p][1][t]) +
                    (pbuf[p][2][t] + pbuf[p][3][t]);
        hv = fast_tanh(xw0 + sum);
        op[0] = hv; op += H;                  // outputs[b,s,t]
        hsh[t] = (_Float16)hv;                // consumed only by own wave

        xw0 = xw1; xw1 = xwn;
    }
    out[(size_t)B * S * H + (size_t)b * H + t] = hv;   // h_last
}

// ---------------------------------------------------------------------------
extern "C" void kernel_launch(void* const* d_in, const int* in_sizes, int n_in,
                              void* d_out, int out_size, void* d_ws, size_t ws_size,
                              hipStream_t stream) {
    const float* x   = (const float*)d_in[0];
    const float* Wxw = (const float*)d_in[1];
    const float* Wxb = (const float*)d_in[2];
    const float* Whw = (const float*)d_in[3];
    float* out = (float*)d_out;

    dim3 g1(B * S / TM, H / TN);   // 1024 x 4
    phase1_gemm<<<g1, 256, 0, stream>>>(x, Wxw, Wxb, out);
    phase2_rnn<<<B, 256, 0, stream>>>(Whw, out);
}